// Round 4
// baseline (991.100 us; speedup 1.0000x reference)
//
#include <hip/hip_runtime.h>
#include <math.h>

// GAU block. N=8, S=2048, D=768, DK=128, 2D=1536. NS=16384 rows.
// Round 10: retry the 256x256 8-phase counted-vmcnt template on PV + UV only,
// with the LDS double-buffer split into FOUR SEPARATE __shared__ arrays
// (As0/As1/Bs0/Bs1). Theory: r7/r8's single As[2][...] array with runtime
// offsets defeated alias analysis -> compiler inserted conservative vmcnt(0)
// before ds_reads of the compute buffer (which may-alias the in-flight
// global_load_lds DMA into the other buffer) -> every phase stalled on HBM
// latency (MfmaUtil 21%, VALUBusy 10%, pins made no difference). Separate
// objects give the waitcnt pass provable non-aliasing. Everything else is
// the proven round-9 825us structure (128x128 GEMMs + XCD swizzle).

typedef __bf16 bf16x8 __attribute__((ext_vector_type(8)));
typedef float  f32x4  __attribute__((ext_vector_type(4)));

__device__ __forceinline__ float silu_f(float v) { return v / (1.0f + __expf(-v)); }
__device__ __forceinline__ float sigmoid_f(float v) { return 1.0f / (1.0f + __expf(-v)); }

__device__ __forceinline__ unsigned short f2bf(float f) {
    union { float f; unsigned u; } v; v.f = f;
    unsigned r = v.u + 0x7fff + ((v.u >> 16) & 1);
    return (unsigned short)(r >> 16);
}
__device__ __forceinline__ float bf2f(unsigned short h) {
    union { unsigned u; float f; } v; v.u = ((unsigned)h) << 16; return v.f;
}

__device__ __forceinline__ void gload_lds16(const void* g, void* l) {
    __builtin_amdgcn_global_load_lds((const __attribute__((address_space(1))) char*)g,
                                     (__attribute__((address_space(3))) char*)l, 16, 0, 0);
}

// XCD-aware bijective block swizzle. Every per-z grid in this file has
// gx*gy % 8 == 0. Confirmed: -21..27% FETCH_SIZE on the PV GEMM.
__device__ __forceinline__ void xcd_swizzle(int& bx, int& by) {
    const int nbx = gridDim.x;
    int flat = by * nbx + bx;
    const int per = (nbx * gridDim.y) >> 3;
    flat = (flat & 7) * per + (flat >> 3);
    bx = flat % nbx;
    by = flat / nbx;
}

// ---------------------------------------------------------------------------
// 128x128 template (round 9, 825us baseline) — all GEMMs except PV/UV.
// ---------------------------------------------------------------------------
template <int EPI, bool DUAL>
__global__ __launch_bounds__(256) void mfma_gemm(
    const unsigned short* __restrict__ A,  int lda, long sA,
    const unsigned short* __restrict__ Bt, int ldb, long sB,
    const unsigned short* __restrict__ A2,
    const unsigned short* __restrict__ Bt2,
    const float* __restrict__ bias,
    const float* __restrict__ aux, long sAux,
    float* __restrict__ aux2,
    void* __restrict__ P0, long sP0,
    void* __restrict__ P1,
    int N, int K)
{
    __shared__ unsigned short As[128 * 64];
    __shared__ unsigned short Bs[128 * 64];
    const int tid  = threadIdx.x;
    const int lane = tid & 63;
    const int wave = tid >> 6;
    const int z    = blockIdx.z;
    int bx = blockIdx.x, by = blockIdx.y;
    xcd_swizzle(bx, by);
    const int row0 = by * 128;
    const int col0 = bx * 128;

    int c_r[4], c_g[4];
    unsigned short* alp[4];
    unsigned short* blp[4];
#pragma unroll
    for (int ci = 0; ci < 4; ++ci) {
        const int c = ci * 256 + tid;
        const int r = c >> 3;
        c_r[ci] = r;
        c_g[ci] = (c & 7) ^ (r & 7);
        alp[ci] = &As[c * 8];
        blp[ci] = &Bs[c * 8];
    }

    const int wr = (wave >> 1) * 64;
    const int wc = (wave & 1) * 64;
    const int fm  = lane & 15;
    const int kbi = lane >> 4;
    const int er  = kbi * 4;

    int aoff[2][4], boff[2][4];
#pragma unroll
    for (int b = 0; b < 2; ++b)
#pragma unroll
        for (int i = 0; i < 4; ++i) {
            const int r = wr + i * 16 + fm;
            aoff[b][i] = r * 64 + (((b * 4 + kbi) ^ (r & 7)) * 8);
            const int n = wc + i * 16 + fm;
            boff[b][i] = n * 64 + (((b * 4 + kbi) ^ (n & 7)) * 8);
        }

    f32x4 acc[4][4];
#pragma unroll
    for (int i = 0; i < 4; ++i)
#pragma unroll
        for (int j = 0; j < 4; ++j) acc[i][j] = (f32x4){0.f, 0.f, 0.f, 0.f};

    const int npass = DUAL ? 2 : 1;
    for (int pass = 0; pass < npass; ++pass) {
        const unsigned short* Ab = (pass ? A2  : A)  + (size_t)z * sA;
        const unsigned short* Bb = (pass ? Bt2 : Bt) + (size_t)z * sB;
        const unsigned short* ag[4];
        const unsigned short* bg[4];
#pragma unroll
        for (int ci = 0; ci < 4; ++ci) {
            ag[ci] = Ab + (size_t)(row0 + c_r[ci]) * lda + c_g[ci] * 8;
            bg[ci] = Bb + (size_t)(col0 + c_r[ci]) * ldb + c_g[ci] * 8;
        }
        for (int k0 = 0; k0 < K; k0 += 64) {
#pragma unroll
            for (int ci = 0; ci < 4; ++ci) { gload_lds16(ag[ci], alp[ci]); ag[ci] += 64; }
#pragma unroll
            for (int ci = 0; ci < 4; ++ci) { gload_lds16(bg[ci], blp[ci]); bg[ci] += 64; }
            __syncthreads();
#pragma unroll
            for (int b = 0; b < 2; ++b) {
                bf16x8 a[4], bb[4];
#pragma unroll
                for (int i = 0; i < 4; ++i) a[i]  = *(const bf16x8*)&As[aoff[b][i]];
#pragma unroll
                for (int j = 0; j < 4; ++j) bb[j] = *(const bf16x8*)&Bs[boff[b][j]];
#pragma unroll
                for (int i = 0; i < 4; ++i)
#pragma unroll
                    for (int j = 0; j < 4; ++j)
                        acc[i][j] = __builtin_amdgcn_mfma_f32_16x16x32_bf16(
                            a[i], bb[j], acc[i][j], 0, 0, 0);
            }
            __syncthreads();
        }
    }

    if (EPI == 1) {
        const float* qb = aux + (size_t)z * sAux;
        unsigned short* Eb = (unsigned short*)P0 + (size_t)z * sP0;
#pragma unroll
        for (int i = 0; i < 4; ++i) {
            float rs[4] = {0.f, 0.f, 0.f, 0.f};
#pragma unroll
            for (int j = 0; j < 4; ++j) {
                const int n = col0 + wc + j * 16 + fm;
#pragma unroll
                for (int reg = 0; reg < 4; ++reg) {
                    const int m = row0 + wr + i * 16 + er + reg;
                    int d = n - m;
                    d = d < -5 ? -5 : (d > 5 ? 5 : d);
                    const float v =
                        __expf((acc[i][j][reg] + qb[m * 11 + d + 5]) * 0.0625f);
                    const unsigned short h = f2bf(v);
                    Eb[(size_t)m * N + n] = h;
                    rs[reg] += bf2f(h);
                }
            }
#pragma unroll
            for (int reg = 0; reg < 4; ++reg) {
                float s = rs[reg];
                s += __shfl_xor(s, 1); s += __shfl_xor(s, 2);
                s += __shfl_xor(s, 4); s += __shfl_xor(s, 8);
                if (fm == 0) {
                    const int m = row0 + wr + i * 16 + er + reg;
                    aux2[((size_t)(z * 2048 + m)) * 32 + bx * 2 + (wave & 1)] = s;
                }
            }
        }
    } else if (EPI == 2) {
        unsigned short* Cb = (unsigned short*)P0;
#pragma unroll
        for (int j = 0; j < 4; ++j) {
            const int n = col0 + wc + j * 16 + fm;
            const float bb = bias[n];
#pragma unroll
            for (int i = 0; i < 4; ++i) {
                const int m0 = row0 + wr + i * 16 + er;
#pragma unroll
                for (int reg = 0; reg < 4; ++reg)
                    Cb[(size_t)(m0 + reg) * N + n] = f2bf(acc[i][j][reg] + bb);
            }
        }
    } else if (EPI == 5) {
        float* Zf = (float*)P0;
#pragma unroll
        for (int j = 0; j < 4; ++j) {
            const int n = col0 + wc + j * 16 + fm;
            const float bb = bias[n];
#pragma unroll
            for (int i = 0; i < 4; ++i) {
                const int m0 = row0 + wr + i * 16 + er;
#pragma unroll
                for (int reg = 0; reg < 4; ++reg)
                    Zf[(size_t)(m0 + reg) * N + n] = silu_f(acc[i][j][reg] + bb);
            }
        }
    } else if (EPI == 6) {
        float* Of = (float*)P0;
        unsigned short* Ob = (unsigned short*)P1;
#pragma unroll
        for (int j = 0; j < 4; ++j) {
            const int n = col0 + wc + j * 16 + fm;
            const float bb = bias[n];
#pragma unroll
            for (int i = 0; i < 4; ++i) {
                const int m0 = row0 + wr + i * 16 + er;
#pragma unroll
                for (int reg = 0; reg < 4; ++reg) {
                    const float v = acc[i][j][reg] + bb;
                    const size_t idx = (size_t)(m0 + reg) * N + n;
                    Of[idx] = v;
                    Ob[idx] = f2bf(v);
                }
            }
        }
    } else if (EPI == 7) {
        float* Of = (float*)P0;
        const float* res = aux;
#pragma unroll
        for (int j = 0; j < 4; ++j) {
            const int n = col0 + wc + j * 16 + fm;
            const float bb = bias[n];
#pragma unroll
            for (int i = 0; i < 4; ++i) {
                const int m0 = row0 + wr + i * 16 + er;
#pragma unroll
                for (int reg = 0; reg < 4; ++reg) {
                    const float g = sigmoid_f(acc[i][j][reg] + bb);
                    const size_t idx = (size_t)(m0 + reg) * N + n;
                    Of[idx] = g * Of[idx] + (1.0f - g) * res[idx];
                }
            }
        }
    }
}

// ---------------------------------------------------------------------------
// 256x256 8-phase counted-vmcnt template, v2: four SEPARATE __shared__
// buffers so the waitcnt pass can prove ds_reads of the compute buffer don't
// alias the in-flight global_load_lds DMA into the prefetch buffer.
// BK=64, 512 thr / 8 waves (2Mx4N), per-wave 128x64 = acc[8][4], LDS 128KB.
// Schedule identical to r8 (verified correct twice). vmcnt(4) at ph3/ph7;
// vmcnt(0) only in the final iteration. Used for EPI 0 (PV) and 8 (UV).
// ---------------------------------------------------------------------------
#define BAR()  __builtin_amdgcn_s_barrier()
#define PIN()  __builtin_amdgcn_sched_barrier(0)
#define LGK0() asm volatile("s_waitcnt lgkmcnt(0)" ::: "memory")
#define LGK8() asm volatile("s_waitcnt lgkmcnt(8)" ::: "memory")
#define VMC4() asm volatile("s_waitcnt vmcnt(4)" ::: "memory")
#define VMC0() asm volatile("s_waitcnt vmcnt(0)" ::: "memory")

template <int EPI>
__global__ __launch_bounds__(512, 2) void gemm256(
    const unsigned short* __restrict__ A,  int lda, long sA,
    const unsigned short* __restrict__ Bt, int ldb, long sB,
    const float* __restrict__ bias,
    float* __restrict__ aux2,
    void* __restrict__ P0, long sP0,
    void* __restrict__ P1,
    int N, int K)
{
    __shared__ unsigned short As0[16384];
    __shared__ unsigned short As1[16384];
    __shared__ unsigned short Bs0[16384];
    __shared__ unsigned short Bs1[16384];
    const int tid  = threadIdx.x;
    const int lane = tid & 63;
    const int wave = tid >> 6;
    const int z    = blockIdx.z;
    int bx = blockIdx.x, by = blockIdx.y;
    xcd_swizzle(bx, by);
    const int row0 = by * 256;
    const int col0 = bx * 256;

    const int wr  = (wave >> 2) * 128;   // 2 waves in M
    const int wc  = (wave & 3) * 64;     // 4 waves in N
    const int fm  = lane & 15;
    const int kbi = lane >> 4;
    const int er  = kbi * 4;

    const int sw0  = (kbi ^ (fm & 7)) * 8;
    const int sw1  = ((4 + kbi) ^ (fm & 7)) * 8;
    const int aof0 = (wr + fm) * 64 + sw0;
    const int aof1 = (wr + fm) * 64 + sw1;
    const int bof0 = (wc + fm) * 64 + sw0;
    const int bof1 = (wc + fm) * 64 + sw1;

    const int r0s = tid >> 3;
    const int g0  = ((tid & 7) ^ (r0s & 7)) * 8;
    const int r1s = r0s + 64;
    const int g1  = ((tid & 7) ^ (r1s & 7)) * 8;
    const int l0  = tid * 8;
    const int l1  = tid * 8 + 4096;

    const unsigned short* Abase = A  + (size_t)z * sA + (size_t)row0 * lda;
    const unsigned short* Bbase = Bt + (size_t)z * sB + (size_t)col0 * ldb;

#define STAGE_A(arr, h, t) do {                                               \
    const unsigned short* _p = Abase + (size_t)((h) * 128) * lda + (t) * 64;  \
    gload_lds16(_p + (size_t)r0s * lda + g0, &arr[(h) * 8192 + l0]);          \
    gload_lds16(_p + (size_t)r1s * lda + g1, &arr[(h) * 8192 + l1]);          \
} while (0)

#define STAGE_B(arr, h, t) do {                                               \
    const unsigned short* _p = Bbase + (size_t)((h) * 128) * ldb + (t) * 64;  \
    gload_lds16(_p + (size_t)r0s * ldb + g0, &arr[(h) * 8192 + l0]);          \
    gload_lds16(_p + (size_t)r1s * ldb + g1, &arr[(h) * 8192 + l1]);          \
} while (0)

#define LD_A(arr, MH) do {                                                    \
    _Pragma("unroll") for (int f = 0; f < 4; ++f) {                           \
        Aq[0][f] = *(const bf16x8*)&arr[aof0 + ((MH) * 4 + f) * 1024];        \
        Aq[1][f] = *(const bf16x8*)&arr[aof1 + ((MH) * 4 + f) * 1024];        \
    } } while (0)

#define LD_B(arr, NH) do {                                                    \
    _Pragma("unroll") for (int g = 0; g < 2; ++g) {                           \
        Bq[NH][0][g] = *(const bf16x8*)&arr[bof0 + ((NH) * 2 + g) * 1024];    \
        Bq[NH][1][g] = *(const bf16x8*)&arr[bof1 + ((NH) * 2 + g) * 1024];    \
    } } while (0)

#define MFMA_Q(MH, NH) do {                                                   \
    __builtin_amdgcn_s_setprio(1);                                            \
    PIN();                                                                    \
    _Pragma("unroll") for (int kb = 0; kb < 2; ++kb)                          \
    _Pragma("unroll") for (int f = 0; f < 4; ++f)                             \
    _Pragma("unroll") for (int g = 0; g < 2; ++g)                             \
        acc[(MH) * 4 + f][(NH) * 2 + g] =                                     \
            __builtin_amdgcn_mfma_f32_16x16x32_bf16(                          \
                Aq[kb][f], Bq[NH][kb][g], acc[(MH) * 4 + f][(NH) * 2 + g],    \
                0, 0, 0);                                                     \
    PIN();                                                                    \
    __builtin_amdgcn_s_setprio(0);                                            \
} while (0)

    bf16x8 Aq[2][4];      // current quadrant's A frags [kb][f]
    bf16x8 Bq[2][2][2];   // both NH B sets [NH][kb][g]
    f32x4  acc[8][4];
#pragma unroll
    for (int i = 0; i < 8; ++i)
#pragma unroll
        for (int j = 0; j < 4; ++j) acc[i][j] = (f32x4){0.f, 0.f, 0.f, 0.f};

    const int nit = K >> 7;  // K/128, K always a multiple of 128 here

    // prologue: tile0 fully + tile1 B halves; vmcnt(4) -> tile0 landed
    STAGE_A(As0, 0, 0); STAGE_A(As0, 1, 0);
    STAGE_B(Bs0, 0, 0); STAGE_B(Bs0, 1, 0);
    STAGE_B(Bs1, 0, 1); STAGE_B(Bs1, 1, 1);
    PIN();
    VMC4();
    BAR();

    for (int i = 0; i < nit; ++i) {
        const bool more = (i + 1 < nit);
        const int t1 = 2 * i + 1, t2 = 2 * i + 2, t3 = 2 * i + 3;
        // ph0
        LD_A(As0, 0); LD_B(Bs0, 0);
        STAGE_A(As1, 0, t1);
        PIN(); LGK8(); BAR(); LGK0();
        MFMA_Q(0, 0);
        BAR();
        // ph1
        LD_B(Bs0, 1);
        STAGE_A(As1, 1, t1);
        PIN(); BAR(); LGK0();
        MFMA_Q(0, 1);
        BAR();
        // ph2
        LD_A(As0, 1);
        if (more) STAGE_B(Bs0, 0, t2);
        PIN(); BAR(); LGK0();
        MFMA_Q(1, 1);
        BAR();
        // ph3
        if (more) { STAGE_B(Bs0, 1, t2); PIN(); VMC4(); } else { PIN(); VMC0(); }
        BAR();
        MFMA_Q(1, 0);
        BAR();
        // ph4
        LD_A(As1, 0); LD_B(Bs1, 0);
        if (more) STAGE_A(As0, 0, t2);
        PIN(); LGK8(); BAR(); LGK0();
        MFMA_Q(0, 0);
        BAR();
        // ph5
        LD_B(Bs1, 1);
        if (more) STAGE_A(As0, 1, t2);
        PIN(); BAR(); LGK0();
        MFMA_Q(0, 1);
        BAR();
        // ph6
        LD_A(As1, 1);
        if (more) STAGE_B(Bs1, 0, t3);
        PIN(); BAR(); LGK0();
        MFMA_Q(1, 1);
        BAR();
        // ph7
        if (more) { STAGE_B(Bs1, 1, t3); PIN(); VMC4(); } else { PIN(); }
        BAR();
        MFMA_Q(1, 0);
        BAR();
    }

#undef STAGE_A
#undef STAGE_B
#undef LD_A
#undef LD_B
#undef MFMA_Q

    if (EPI == 0) {        // PV: Ub = bf16(acc * inv[m] * bf2f(Ub))
        unsigned short* Ub = (unsigned short*)P0 + (size_t)z * sP0;
        const float* inv = aux2 + (z << 11);
#pragma unroll
        for (int i = 0; i < 8; ++i)
#pragma unroll
            for (int j = 0; j < 4; ++j) {
                const int m0 = row0 + wr + i * 16 + er;
                const int n  = col0 + wc + j * 16 + fm;
#pragma unroll
                for (int reg = 0; reg < 4; ++reg) {
                    const size_t idx = (size_t)(m0 + reg) * N + n;
                    Ub[idx] = f2bf(acc[i][j][reg] * inv[m0 + reg] * bf2f(Ub[idx]));
                }
            }
    } else if (EPI == 8) { // merged U | Vt
        unsigned short* Ub = (unsigned short*)P0;
        unsigned short* Vt = (unsigned short*)P1;
#pragma unroll
        for (int j = 0; j < 4; ++j) {
            const int n = col0 + wc + j * 16 + fm;
            const bool isU = n < 1536;
            const float bb = isU ? bias[n] : aux2[n - 1536];
#pragma unroll
            for (int i = 0; i < 8; ++i) {
                const int m0 = row0 + wr + i * 16 + er;
                if (isU) {
#pragma unroll
                    for (int reg = 0; reg < 4; ++reg)
                        Ub[(size_t)(m0 + reg) * 1536 + n] =
                            f2bf(silu_f(acc[i][j][reg] + bb));
                } else {
                    const int bat = m0 >> 11;
                    const int sl  = m0 & 2047;
                    unsigned short t[4];
#pragma unroll
                    for (int reg = 0; reg < 4; ++reg)
                        t[reg] = f2bf(silu_f(acc[i][j][reg] + bb));
                    *(ushort4*)(Vt + (size_t)bat * 1536 * 2048
                                + (size_t)(n - 1536) * 2048 + sl) = *(const ushort4*)t;
                }
            }
        }
    }
}

// rowsum inverse: inv[r] = 1 / sum_k part[r][k], r in [0,16384)
__global__ __launch_bounds__(256) void reduce_inv(
    const float* __restrict__ part, float* __restrict__ inv)
{
    const int r = blockIdx.x * 256 + threadIdx.x;
    const float4* p = (const float4*)(part + (size_t)r * 32);
    float s = 0.f;
#pragma unroll
    for (int k = 0; k < 8; ++k) {
        float4 v = p[k];
        s += v.x + v.y + v.z + v.w;
    }
    inv[r] = 1.0f / s;
}

// W [K,N] fp32 -> Wt [N,K] bf16 via 32x32 LDS tile. grid (N/32, K/32).
__global__ __launch_bounds__(256) void transpose_w(
    const float* __restrict__ W, unsigned short* __restrict__ Wt, int K, int N)
{
    __shared__ float t[32][33];
    const int tx = threadIdx.x & 31, ty = threadIdx.x >> 5;
    const int kb = blockIdx.y * 32, nb = blockIdx.x * 32;
#pragma unroll
    for (int r = 0; r < 4; ++r)
        t[ty + 8 * r][tx] = W[(size_t)(kb + ty + 8 * r) * N + nb + tx];
    __syncthreads();
#pragma unroll
    for (int r = 0; r < 4; ++r)
        Wt[(size_t)(nb + ty + 8 * r) * K + kb + tx] = f2bf(t[tx][ty + 8 * r]);
}

// fp32 -> bf16, 4 elems/thread
__global__ __launch_bounds__(256) void f32_to_bf16(
    const float* __restrict__ in, unsigned short* __restrict__ o)
{
    const size_t i = ((size_t)blockIdx.x * 256 + threadIdx.x) * 4;
    float4 v = *(const float4*)(in + i);
    ushort4 b;
    b.x = f2bf(v.x); b.y = f2bf(v.y); b.z = f2bf(v.z); b.w = f2bf(v.w);
    *(ushort4*)(o + i) = b;
}

// LayerNorm over 768, bf16 in/out, fp32 stats. grid = 16384 rows.
__global__ __launch_bounds__(256) void ln_bf16(
    const unsigned short* __restrict__ in, const float* __restrict__ g,
    const float* __restrict__ b, unsigned short* __restrict__ out)
{
    const int row = blockIdx.x;
    const unsigned short* p = in + (size_t)row * 768;
    const int tid = threadIdx.x;
    float v0 = bf2f(p[tid]), v1 = bf2f(p[tid + 256]), v2 = bf2f(p[tid + 512]);
    float s = v0 + v1 + v2;
    float q = v0 * v0 + v1 * v1 + v2 * v2;
#pragma unroll
    for (int off = 32; off; off >>= 1) {
        s += __shfl_xor(s, off);
        q += __shfl_xor(q, off);
    }
    __shared__ float ss[4], qq[4];
    const int wid = tid >> 6, lane = tid & 63;
    if (lane == 0) { ss[wid] = s; qq[wid] = q; }
    __syncthreads();
    s = ss[0] + ss[1] + ss[2] + ss[3];
    q = qq[0] + qq[1] + qq[2] + qq[3];
    const float mu  = s * (1.0f / 768.0f);
    const float var = q * (1.0f / 768.0f) - mu * mu;
    const float inv = rsqrtf(var + 1e-5f);
    unsigned short* o = out + (size_t)row * 768;
    o[tid]       = f2bf((v0 - mu) * inv * g[tid]       + b[tid]);
    o[tid + 256] = f2bf((v1 - mu) * inv * g[tid + 256] + b[tid + 256]);
    o[tid + 512] = f2bf((v2 - mu) * inv * g[tid + 512] + b[tid + 512]);
}

// q_pos[i,p] = dot(Z_i*g1+b1, embed_pos[p]); one wave per row (Z fp32).
__global__ __launch_bounds__(256) void qpos_kernel(
    const float* __restrict__ Z, const float* __restrict__ g1,
    const float* __restrict__ b1, const float* __restrict__ ep,
    float* __restrict__ qpos)
{
    const int tid = threadIdx.x;
    const int lane = tid & 63;
    const int wid = tid >> 6;
    const int row = blockIdx.x * 4 + wid;
    const float z0 = Z[(size_t)row * 128 + lane];
    const float z1 = Z[(size_t)row * 128 + 64 + lane];
    const float q0 = z0 * g1[lane] + b1[lane];
    const float q1 = z1 * g1[64 + lane] + b1[64 + lane];
#pragma unroll
    for (int p = 0; p < 11; ++p) {
        float s = q0 * ep[p * 128 + lane] + q1 * ep[p * 128 + 64 + lane];
#pragma unroll
        for (int off = 32; off; off >>= 1) s += __shfl_xor(s, off);
        if (lane == 0) qpos[(size_t)row * 11 + p] = s;
    }
}

// Qb = bf16(Z*g0+b0), Kb = bf16(Z*g2+b2). Z fp32 [16384,128].
__global__ __launch_bounds__(256) void qk_affine(
    const float* __restrict__ Z, const float* __restrict__ gamma,
    const float* __restrict__ beta,
    unsigned short* __restrict__ Qb, unsigned short* __restrict__ Kb)
{
    const int idx = blockIdx.x * 256 + threadIdx.x;
    const int row = idx >> 5;
    const int c   = (idx & 31) * 4;
    float4 z  = *(const float4*)(Z + (size_t)row * 128 + c);
    float4 g0 = *(const float4*)(gamma + c);
    float4 B0 = *(const float4*)(beta + c);
    float4 g2 = *(const float4*)(gamma + 256 + c);
    float4 B2 = *(const float4*)(beta + 256 + c);
    ushort4 q, k;
    q.x = f2bf(z.x * g0.x + B0.x); q.y = f2bf(z.y * g0.y + B0.y);
    q.z = f2bf(z.z * g0.z + B0.z); q.w = f2bf(z.w * g0.w + B0.w);
    k.x = f2bf(z.x * g2.x + B2.x); k.y = f2bf(z.y * g2.y + B2.y);
    k.z = f2bf(z.z * g2.z + B2.z); k.w = f2bf(z.w * g2.w + B2.w);
    *(ushort4*)(Qb + (size_t)row * 128 + c) = q;
    *(ushort4*)(Kb + (size_t)row * 128 + c) = k;
}

// ---------------------------------------------------------------------------
extern "C" void kernel_launch(void* const* d_in, const int* in_sizes, int n_in,
                              void* d_out, int out_size, void* d_ws, size_t ws_size,
                              hipStream_t stream)
{
    const float* seq    = (const float*)d_in[0];
    const float* W_init = (const float*)d_in[3];
    const float* b_init = (const float*)d_in[4];
    const float* ln_g   = (const float*)d_in[5];
    const float* ln_b   = (const float*)d_in[6];
    const float* W_u    = (const float*)d_in[7];
    const float* b_u    = (const float*)d_in[8];
    const float* W_v    = (const float*)d_in[9];
    const float* b_v    = (const float*)d_in[10];
    const float* W_z    = (const float*)d_in[11];
    const float* b_z    = (const float*)d_in[12];
    const float* gamma  = (const float*)d_in[13];
    const float* beta   = (const float*)d_in[14];
    const float* embed  = (const float*)d_in[15];
    const float* W_out  = (const float*)d_in[16];
    const float* b_out  = (const float*)d_in[17];
    const float* W_gate = (const float*)d_in[18];
    const float* b_gate = (const float*)d_in[19];
    float* out = (float*)d_out;

    // workspace (~299 MiB)
    char* ws = (char*)d_ws;
    float* Z    = (float*)ws;                     ws += (size_t)16384 * 128 * 4;
    float* qpos = (float*)ws;                     ws += (size_t)16384 * 11 * 4;
    float* part = (float*)ws;                     ws += (size_t)16384 * 32 * 4;
    float* inv  = (float*)ws;                     ws += (size_t)16384 * 4;
    unsigned short* seq_bf = (unsigned short*)ws; ws += (size_t)16384 * 768 * 2;
    unsigned short* G_bf   = (unsigned short*)ws; ws += (size_t)16384 * 768 * 2;
    unsigned short* x_bf   = (unsigned short*)ws; ws += (size_t)16384 * 768 * 2;
    unsigned short* U_bf   = (unsigned short*)ws; ws += (size_t)16384 * 1536 * 2;
    unsigned short* Vt     = (unsigned short*)ws; ws += (size_t)16384 * 1536 * 2;
    unsigned short* out_bf = (unsigned short*)ws; ws += (size_t)16384 * 768 * 2;
    unsigned short* Qb     = (unsigned short*)ws; ws += (size_t)16384 * 128 * 2;
    unsigned short* Kb     = (unsigned short*)ws; ws += (size_t)16384 * 128 * 2;
    unsigned short* E      = (unsigned short*)ws; ws += (size_t)8 * 2048 * 2048 * 2;
    unsigned short* Wit    = (unsigned short*)ws; ws += (size_t)768 * 768 * 2;
    unsigned short* Wuvt   = (unsigned short*)ws; ws += (size_t)3072 * 768 * 2;
    unsigned short* Wzt    = (unsigned short*)ws; ws += (size_t)128 * 768 * 2;
    unsigned short* Wot    = (unsigned short*)ws; ws += (size_t)768 * 1536 * 2;
    unsigned short* Wgt    = (unsigned short*)ws; ws += (size_t)768 * 1536 * 2;

    const dim3 b256(256);
    const dim3 b512(512);

    // 0. conversions
    f32_to_bf16<<<12288, b256, 0, stream>>>(seq, seq_bf);
    transpose_w<<<dim3(24, 24), b256, 0, stream>>>(W_init, Wit, 768, 768);
    transpose_w<<<dim3(48, 24), b256, 0, stream>>>(W_u, Wuvt, 768, 1536);
    transpose_w<<<dim3(48, 24), b256, 0, stream>>>(W_v, Wuvt + (size_t)1536 * 768, 768, 1536);
    transpose_w<<<dim3(4, 24),  b256, 0, stream>>>(W_z, Wzt, 768, 128);
    transpose_w<<<dim3(24, 48), b256, 0, stream>>>(W_out,  Wot, 1536, 768);
    transpose_w<<<dim3(24, 48), b256, 0, stream>>>(W_gate, Wgt, 1536, 768);

    // 1. G_bf = bf16(seq @ W_init + b_init)   [128^2]
    mfma_gemm<2, false><<<dim3(6, 128), b256, 0, stream>>>(
        seq_bf, 768, 0, Wit, 768, 0, nullptr, nullptr,
        b_init, nullptr, 0, nullptr, G_bf, 0, nullptr, 768, 768);
    // 2. x_bf = LN(G_bf)
    ln_bf16<<<16384, b256, 0, stream>>>(G_bf, ln_g, ln_b, x_bf);
    // 3. merged U | Vt = silu(x @ [W_u|W_v] + [b_u|b_v])   [256^2 v2]
    gemm256<8><<<dim3(12, 64), b512, 0, stream>>>(
        x_bf, 768, 0, Wuvt, 768, 0,
        b_u, (float*)b_v, U_bf, 0, Vt, 3072, 768);
    // 4. Z = silu(x @ W_z + b_z)  (fp32)   [128^2]
    mfma_gemm<5, false><<<dim3(1, 128), b256, 0, stream>>>(
        x_bf, 768, 0, Wzt, 768, 0, nullptr, nullptr,
        b_z, nullptr, 0, nullptr, Z, 0, nullptr, 128, 768);
    // 5. q_pos, Qb/Kb
    qpos_kernel<<<4096, b256, 0, stream>>>(Z, gamma + 128, beta + 128, embed, qpos);
    qk_affine<<<2048, b256, 0, stream>>>(Z, gamma, beta, Qb, Kb);

    // 6. attention; softmax fused (exp + rowsum inv)   [128^2]
    mfma_gemm<1, false><<<dim3(16, 16, 8), b256, 0, stream>>>(
        Qb, 128, 2048L * 128, Kb, 128, 2048L * 128,
        nullptr, nullptr, nullptr,
        qpos, 2048L * 11, part,
        E, 2048L * 2048, nullptr, 2048, 128);
    reduce_inv<<<64, b256, 0, stream>>>(part, inv);
    // PV: Ub = bf16(E @ Vt * inv * U)   [256^2 v2]
    gemm256<0><<<dim3(6, 8, 8), b512, 0, stream>>>(
        E, 2048, 2048L * 2048, Vt, 2048, 1536L * 2048,
        nullptr, inv, U_bf, 2048L * 1536, nullptr, 1536, 2048);

    // 7. out = UV @ W_out + b_out (fp32 -> d_out, bf16 -> out_bf)  [128^2]
    mfma_gemm<6, false><<<dim3(6, 128), b256, 0, stream>>>(
        U_bf, 1536, 0, Wot, 1536, 0, nullptr, nullptr,
        b_out, nullptr, 0, nullptr, out, 0, out_bf, 768, 1536);
    // 8. fused gate: g = sig(out_pre@Wg1 + seq@Wg2 + b); out = g*out + (1-g)*seq
    mfma_gemm<7, true><<<dim3(6, 128), b256, 0, stream>>>(
        out_bf, 768, 0, Wgt, 1536, 0, seq_bf, Wgt + 768,
        b_gate, seq, 0, nullptr, out, 0, nullptr, 768, 768);
}

// Round 5
// 829.463 us; speedup vs baseline: 1.1949x; 1.1949x over previous
//
#include <hip/hip_runtime.h>
#include <math.h>

// GAU block. N=8, S=2048, D=768, DK=128, 2D=1536. NS=16384 rows.
// Round 11: consolidation on the proven round-3/round-9 structure (825us).
// The 256x256 8-phase template is retired: three controlled variants (r7
// no-pins, r8 pins+clobbers, r10 separate LDS objects) all landed at
// MfmaUtil ~21% / VALUBusy ~10% -> structural failure (insufficient prefetch
// distance + 1 block/CU at 128KB LDS leaves the barrier convoy unhidden),
// not fixable at HIP source level without disasm evidence.
// This round, launch/serialization cuts with certain mechanisms:
//  - Z GEMM merged into UV (B = [Wu|Wv|Wz]^T, N=3200, grid 25x128; the
//    old Z launch ran 128 blocks = half the chip idle)
//  - 6 weight-transpose launches -> 1 flat-grid prep_w
//  - qpos + qk_affine -> 1 kernel (single Z read)
// 15 launches -> 11. All GEMM math bitwise-identical to the 825us run.

typedef __bf16 bf16x8 __attribute__((ext_vector_type(8)));
typedef float  f32x4  __attribute__((ext_vector_type(4)));

__device__ __forceinline__ float silu_f(float v) { return v / (1.0f + __expf(-v)); }
__device__ __forceinline__ float sigmoid_f(float v) { return 1.0f / (1.0f + __expf(-v)); }

__device__ __forceinline__ unsigned short f2bf(float f) {
    union { float f; unsigned u; } v; v.f = f;
    unsigned r = v.u + 0x7fff + ((v.u >> 16) & 1);
    return (unsigned short)(r >> 16);
}
__device__ __forceinline__ float bf2f(unsigned short h) {
    union { unsigned u; float f; } v; v.u = ((unsigned)h) << 16; return v.f;
}

__device__ __forceinline__ void gload_lds16(const void* g, void* l) {
    __builtin_amdgcn_global_load_lds((const __attribute__((address_space(1))) char*)g,
                                     (__attribute__((address_space(3))) char*)l, 16, 0, 0);
}

// XCD-aware bijective block swizzle. Every per-z grid in this file has
// gx*gy % 8 == 0. Confirmed twice: -21..27% FETCH_SIZE on the PV GEMM.
__device__ __forceinline__ void xcd_swizzle(int& bx, int& by) {
    const int nbx = gridDim.x;
    int flat = by * nbx + bx;
    const int per = (nbx * gridDim.y) >> 3;
    flat = (flat & 7) * per + (flat >> 3);
    bx = flat % nbx;
    by = flat / nbx;
}

// ---------------------------------------------------------------------------
// bf16 MFMA GEMM: acc[M,N] = A[M,K] @ Bt[N,K]^T (+2nd pass if DUAL).
// 128x128 tile, BK=64, 256 thr / 4 waves 2x2, each wave 4x4 of 16x16x32.
// LDS rows hold 8 16B slots, stored at slot p = s ^ (r&7) -> 2-way reads.
// Epilogues:
//  0 PV   : Ub[m,n] = bf16(acc * inv[z*2048+m] * bf2f(Ub[m,n]))  (aux2=inv)
//  1 QK   : E[m,n] = bf16(exp((acc+qpos[m,clip(n-m)+5])/16)); 16-lane partial
//           row sums -> aux2[(z*2048+m)*32 + bx*2 + (wave&1)]     (aux=qpos)
//  2 BIAS : Cbf[m,n] = bf16(acc + bias[n])
//  6 OUT  : Of[m,n] = acc + bias[n]  AND  Obf[m,n] = bf16(same)
//  7 GATE : g = sig(acc + bias[n]); Of[m,n] = g*Of + (1-g)*res    (aux=res)
//  8 UVZ  : n<1536: Ub = bf16(silu(acc+bias[n])); 1536<=n<3072:
//           Vt[bat][(n-1536)*2048+(m&2047)] = bf16(silu(acc+bias2[n-1536]));
//           n>=3072: Zf[m*128+(n-3072)] = silu(acc+aux[n-3072]) fp32 (aux2=Zf)
// ---------------------------------------------------------------------------
template <int EPI, bool DUAL>
__global__ __launch_bounds__(256) void mfma_gemm(
    const unsigned short* __restrict__ A,  int lda, long sA,
    const unsigned short* __restrict__ Bt, int ldb, long sB,
    const unsigned short* __restrict__ A2,
    const unsigned short* __restrict__ Bt2,
    const float* __restrict__ bias,
    const float* __restrict__ bias2,
    const float* __restrict__ aux, long sAux,
    float* __restrict__ aux2,
    void* __restrict__ P0, long sP0,
    void* __restrict__ P1,
    int N, int K)
{
    __shared__ unsigned short As[128 * 64];
    __shared__ unsigned short Bs[128 * 64];
    const int tid  = threadIdx.x;
    const int lane = tid & 63;
    const int wave = tid >> 6;
    const int z    = blockIdx.z;
    int bx = blockIdx.x, by = blockIdx.y;
    xcd_swizzle(bx, by);
    const int row0 = by * 128;
    const int col0 = bx * 128;

    int c_r[4], c_g[4];
    unsigned short* alp[4];
    unsigned short* blp[4];
#pragma unroll
    for (int ci = 0; ci < 4; ++ci) {
        const int c = ci * 256 + tid;
        const int r = c >> 3;
        c_r[ci] = r;
        c_g[ci] = (c & 7) ^ (r & 7);   // global slot fetched into LDS pos c
        alp[ci] = &As[c * 8];
        blp[ci] = &Bs[c * 8];
    }

    const int wr = (wave >> 1) * 64;
    const int wc = (wave & 1) * 64;
    const int fm  = lane & 15;
    const int kbi = lane >> 4;
    const int er  = kbi * 4;

    int aoff[2][4], boff[2][4];
#pragma unroll
    for (int b = 0; b < 2; ++b)
#pragma unroll
        for (int i = 0; i < 4; ++i) {
            const int r = wr + i * 16 + fm;
            aoff[b][i] = r * 64 + (((b * 4 + kbi) ^ (r & 7)) * 8);
            const int n = wc + i * 16 + fm;
            boff[b][i] = n * 64 + (((b * 4 + kbi) ^ (n & 7)) * 8);
        }

    f32x4 acc[4][4];
#pragma unroll
    for (int i = 0; i < 4; ++i)
#pragma unroll
        for (int j = 0; j < 4; ++j) acc[i][j] = (f32x4){0.f, 0.f, 0.f, 0.f};

    const int npass = DUAL ? 2 : 1;
    for (int pass = 0; pass < npass; ++pass) {
        const unsigned short* Ab = (pass ? A2  : A)  + (size_t)z * sA;
        const unsigned short* Bb = (pass ? Bt2 : Bt) + (size_t)z * sB;
        const unsigned short* ag[4];
        const unsigned short* bg[4];
#pragma unroll
        for (int ci = 0; ci < 4; ++ci) {
            ag[ci] = Ab + (size_t)(row0 + c_r[ci]) * lda + c_g[ci] * 8;
            bg[ci] = Bb + (size_t)(col0 + c_r[ci]) * ldb + c_g[ci] * 8;
        }
        for (int k0 = 0; k0 < K; k0 += 64) {
#pragma unroll
            for (int ci = 0; ci < 4; ++ci) { gload_lds16(ag[ci], alp[ci]); ag[ci] += 64; }
#pragma unroll
            for (int ci = 0; ci < 4; ++ci) { gload_lds16(bg[ci], blp[ci]); bg[ci] += 64; }
            __syncthreads();
#pragma unroll
            for (int b = 0; b < 2; ++b) {
                bf16x8 a[4], bb[4];
#pragma unroll
                for (int i = 0; i < 4; ++i) a[i]  = *(const bf16x8*)&As[aoff[b][i]];
#pragma unroll
                for (int j = 0; j < 4; ++j) bb[j] = *(const bf16x8*)&Bs[boff[b][j]];
#pragma unroll
                for (int i = 0; i < 4; ++i)
#pragma unroll
                    for (int j = 0; j < 4; ++j)
                        acc[i][j] = __builtin_amdgcn_mfma_f32_16x16x32_bf16(
                            a[i], bb[j], acc[i][j], 0, 0, 0);
            }
            __syncthreads();
        }
    }

    if (EPI == 0) {
        unsigned short* Ub = (unsigned short*)P0 + (size_t)z * sP0;
        const float* inv = aux2 + (z << 11);
#pragma unroll
        for (int i = 0; i < 4; ++i)
#pragma unroll
            for (int j = 0; j < 4; ++j) {
                const int m0 = row0 + wr + i * 16 + er;
                const int n  = col0 + wc + j * 16 + fm;
#pragma unroll
                for (int reg = 0; reg < 4; ++reg) {
                    const size_t idx = (size_t)(m0 + reg) * N + n;
                    Ub[idx] = f2bf(acc[i][j][reg] * inv[m0 + reg] * bf2f(Ub[idx]));
                }
            }
    } else if (EPI == 1) {
        const float* qb = aux + (size_t)z * sAux;
        unsigned short* Eb = (unsigned short*)P0 + (size_t)z * sP0;
#pragma unroll
        for (int i = 0; i < 4; ++i) {
            float rs[4] = {0.f, 0.f, 0.f, 0.f};
#pragma unroll
            for (int j = 0; j < 4; ++j) {
                const int n = col0 + wc + j * 16 + fm;
#pragma unroll
                for (int reg = 0; reg < 4; ++reg) {
                    const int m = row0 + wr + i * 16 + er + reg;
                    int d = n - m;
                    d = d < -5 ? -5 : (d > 5 ? 5 : d);
                    const float v =
                        __expf((acc[i][j][reg] + qb[m * 11 + d + 5]) * 0.0625f);
                    const unsigned short h = f2bf(v);
                    Eb[(size_t)m * N + n] = h;
                    rs[reg] += bf2f(h);
                }
            }
#pragma unroll
            for (int reg = 0; reg < 4; ++reg) {
                float s = rs[reg];
                s += __shfl_xor(s, 1); s += __shfl_xor(s, 2);
                s += __shfl_xor(s, 4); s += __shfl_xor(s, 8);
                if (fm == 0) {
                    const int m = row0 + wr + i * 16 + er + reg;
                    aux2[((size_t)(z * 2048 + m)) * 32 + bx * 2 + (wave & 1)] = s;
                }
            }
        }
    } else if (EPI == 2) {
        unsigned short* Cb = (unsigned short*)P0;
#pragma unroll
        for (int j = 0; j < 4; ++j) {
            const int n = col0 + wc + j * 16 + fm;
            const float bb = bias[n];
#pragma unroll
            for (int i = 0; i < 4; ++i) {
                const int m0 = row0 + wr + i * 16 + er;
#pragma unroll
                for (int reg = 0; reg < 4; ++reg)
                    Cb[(size_t)(m0 + reg) * N + n] = f2bf(acc[i][j][reg] + bb);
            }
        }
    } else if (EPI == 6) {
        float* Of = (float*)P0;
        unsigned short* Ob = (unsigned short*)P1;
#pragma unroll
        for (int j = 0; j < 4; ++j) {
            const int n = col0 + wc + j * 16 + fm;
            const float bb = bias[n];
#pragma unroll
            for (int i = 0; i < 4; ++i) {
                const int m0 = row0 + wr + i * 16 + er;
#pragma unroll
                for (int reg = 0; reg < 4; ++reg) {
                    const float v = acc[i][j][reg] + bb;
                    const size_t idx = (size_t)(m0 + reg) * N + n;
                    Of[idx] = v;
                    Ob[idx] = f2bf(v);
                }
            }
        }
    } else if (EPI == 7) {
        float* Of = (float*)P0;
        const float* res = aux;
#pragma unroll
        for (int j = 0; j < 4; ++j) {
            const int n = col0 + wc + j * 16 + fm;
            const float bb = bias[n];
#pragma unroll
            for (int i = 0; i < 4; ++i) {
                const int m0 = row0 + wr + i * 16 + er;
#pragma unroll
                for (int reg = 0; reg < 4; ++reg) {
                    const float g = sigmoid_f(acc[i][j][reg] + bb);
                    const size_t idx = (size_t)(m0 + reg) * N + n;
                    Of[idx] = g * Of[idx] + (1.0f - g) * res[idx];
                }
            }
        }
    } else {  // EPI 8: merged U | Vt | Z  (block-uniform: bx<12 U, <24 Vt, 24 Z)
        unsigned short* Ub = (unsigned short*)P0;
        unsigned short* Vt = (unsigned short*)P1;
        float* Zf = aux2;
#pragma unroll
        for (int j = 0; j < 4; ++j) {
            const int n = col0 + wc + j * 16 + fm;
#pragma unroll
            for (int i = 0; i < 4; ++i) {
                const int m0 = row0 + wr + i * 16 + er;
                if (n < 1536) {
                    const float bb = bias[n];
#pragma unroll
                    for (int reg = 0; reg < 4; ++reg)
                        Ub[(size_t)(m0 + reg) * 1536 + n] =
                            f2bf(silu_f(acc[i][j][reg] + bb));
                } else if (n < 3072) {
                    const float bb = bias2[n - 1536];
                    const int bat = m0 >> 11;
                    const int sl  = m0 & 2047;
                    unsigned short t[4];
#pragma unroll
                    for (int reg = 0; reg < 4; ++reg)
                        t[reg] = f2bf(silu_f(acc[i][j][reg] + bb));
                    *(ushort4*)(Vt + (size_t)bat * 1536 * 2048
                                + (size_t)(n - 1536) * 2048 + sl) = *(const ushort4*)t;
                } else {
                    const float bb = aux[n - 3072];
#pragma unroll
                    for (int reg = 0; reg < 4; ++reg)
                        Zf[(size_t)(m0 + reg) * 128 + (n - 3072)] =
                            silu_f(acc[i][j][reg] + bb);
                }
            }
        }
    }
}

// rowsum inverse: inv[r] = 1 / sum_k part[r][k], r in [0,16384)
__global__ __launch_bounds__(256) void reduce_inv(
    const float* __restrict__ part, float* __restrict__ inv)
{
    const int r = blockIdx.x * 256 + threadIdx.x;
    const float4* p = (const float4*)(part + (size_t)r * 32);
    float s = 0.f;
#pragma unroll
    for (int k = 0; k < 8; ++k) {
        float4 v = p[k];
        s += v.x + v.y + v.z + v.w;
    }
    inv[r] = 1.0f / s;
}

// All weight transposes in one launch. Jobs (32x32-tile grids, flat-packed):
// [0,576) W_init->Wit; [576,1728) W_u->Wuvzt; [1728,2880) W_v->Wuvzt+1536*768;
// [2880,2976) W_z->Wuvzt+3072*768; [2976,4128) W_out->Wot; [4128,5280) W_gate->Wgt.
__global__ __launch_bounds__(256) void prep_w(
    const float* __restrict__ Wi, const float* __restrict__ Wu,
    const float* __restrict__ Wv, const float* __restrict__ Wz,
    const float* __restrict__ Wo, const float* __restrict__ Wg,
    unsigned short* __restrict__ Wit, unsigned short* __restrict__ Wuvzt,
    unsigned short* __restrict__ Wot, unsigned short* __restrict__ Wgt)
{
    const int b = blockIdx.x;
    const float* W;
    unsigned short* Wt;
    int K, N, t;
    if (b < 576)       { W = Wi; Wt = Wit;  K = 768;  N = 768;  t = b; }
    else if (b < 1728) { W = Wu; Wt = Wuvzt;                 K = 768;  N = 1536; t = b - 576; }
    else if (b < 2880) { W = Wv; Wt = Wuvzt + (size_t)1536 * 768; K = 768; N = 1536; t = b - 1728; }
    else if (b < 2976) { W = Wz; Wt = Wuvzt + (size_t)3072 * 768; K = 768; N = 128;  t = b - 2880; }
    else if (b < 4128) { W = Wo; Wt = Wot;  K = 1536; N = 768;  t = b - 2976; }
    else               { W = Wg; Wt = Wgt;  K = 1536; N = 768;  t = b - 4128; }
    const int nbx = N >> 5;
    const int kb = (t / nbx) * 32, nb = (t % nbx) * 32;

    __shared__ float tile[32][33];
    const int tx = threadIdx.x & 31, ty = threadIdx.x >> 5;
#pragma unroll
    for (int r = 0; r < 4; ++r)
        tile[ty + 8 * r][tx] = W[(size_t)(kb + ty + 8 * r) * N + nb + tx];
    __syncthreads();
#pragma unroll
    for (int r = 0; r < 4; ++r)
        Wt[(size_t)(nb + ty + 8 * r) * K + kb + tx] = f2bf(tile[tx][ty + 8 * r]);
}

// fp32 -> bf16, 4 elems/thread
__global__ __launch_bounds__(256) void f32_to_bf16(
    const float* __restrict__ in, unsigned short* __restrict__ o)
{
    const size_t i = ((size_t)blockIdx.x * 256 + threadIdx.x) * 4;
    float4 v = *(const float4*)(in + i);
    ushort4 b;
    b.x = f2bf(v.x); b.y = f2bf(v.y); b.z = f2bf(v.z); b.w = f2bf(v.w);
    *(ushort4*)(o + i) = b;
}

// LayerNorm over 768, bf16 in/out, fp32 stats. grid = 16384 rows.
__global__ __launch_bounds__(256) void ln_bf16(
    const unsigned short* __restrict__ in, const float* __restrict__ g,
    const float* __restrict__ b, unsigned short* __restrict__ out)
{
    const int row = blockIdx.x;
    const unsigned short* p = in + (size_t)row * 768;
    const int tid = threadIdx.x;
    float v0 = bf2f(p[tid]), v1 = bf2f(p[tid + 256]), v2 = bf2f(p[tid + 512]);
    float s = v0 + v1 + v2;
    float q = v0 * v0 + v1 * v1 + v2 * v2;
#pragma unroll
    for (int off = 32; off; off >>= 1) {
        s += __shfl_xor(s, off);
        q += __shfl_xor(q, off);
    }
    __shared__ float ss[4], qq[4];
    const int wid = tid >> 6, lane = tid & 63;
    if (lane == 0) { ss[wid] = s; qq[wid] = q; }
    __syncthreads();
    s = ss[0] + ss[1] + ss[2] + ss[3];
    q = qq[0] + qq[1] + qq[2] + qq[3];
    const float mu  = s * (1.0f / 768.0f);
    const float var = q * (1.0f / 768.0f) - mu * mu;
    const float inv = rsqrtf(var + 1e-5f);
    unsigned short* o = out + (size_t)row * 768;
    o[tid]       = f2bf((v0 - mu) * inv * g[tid]       + b[tid]);
    o[tid + 256] = f2bf((v1 - mu) * inv * g[tid + 256] + b[tid + 256]);
    o[tid + 512] = f2bf((v2 - mu) * inv * g[tid + 512] + b[tid + 512]);
}

// Merged Q/K affine + q_pos. One wave per row (4 rows/block, grid 4096).
// Per row: Qb = bf16(Z*g0+b0), Kb = bf16(Z*g2+b2),
// qpos[row,p] = dot(Z*g1+b1, embed_pos[p]), p in [0,11).
__global__ __launch_bounds__(256) void qk_prep(
    const float* __restrict__ Z, const float* __restrict__ gamma,
    const float* __restrict__ beta, const float* __restrict__ ep,
    float* __restrict__ qpos,
    unsigned short* __restrict__ Qb, unsigned short* __restrict__ Kb)
{
    const int tid = threadIdx.x;
    const int lane = tid & 63;
    const int wid = tid >> 6;
    const int row = blockIdx.x * 4 + wid;
    const float z0 = Z[(size_t)row * 128 + lane];
    const float z1 = Z[(size_t)row * 128 + 64 + lane];
    // Q (gamma0/beta0) and K (gamma2/beta2)
    Qb[(size_t)row * 128 + lane]      = f2bf(z0 * gamma[lane]       + beta[lane]);
    Qb[(size_t)row * 128 + 64 + lane] = f2bf(z1 * gamma[64 + lane]  + beta[64 + lane]);
    Kb[(size_t)row * 128 + lane]      = f2bf(z0 * gamma[256 + lane]      + beta[256 + lane]);
    Kb[(size_t)row * 128 + 64 + lane] = f2bf(z1 * gamma[256 + 64 + lane] + beta[256 + 64 + lane]);
    // q_pos (gamma1/beta1)
    const float q0 = z0 * gamma[128 + lane] + beta[128 + lane];
    const float q1 = z1 * gamma[192 + lane] + beta[192 + lane];
#pragma unroll
    for (int p = 0; p < 11; ++p) {
        float s = q0 * ep[p * 128 + lane] + q1 * ep[p * 128 + 64 + lane];
#pragma unroll
        for (int off = 32; off; off >>= 1) s += __shfl_xor(s, off);
        if (lane == 0) qpos[(size_t)row * 11 + p] = s;
    }
}

// ---------------------------------------------------------------------------
extern "C" void kernel_launch(void* const* d_in, const int* in_sizes, int n_in,
                              void* d_out, int out_size, void* d_ws, size_t ws_size,
                              hipStream_t stream)
{
    const float* seq    = (const float*)d_in[0];
    const float* W_init = (const float*)d_in[3];
    const float* b_init = (const float*)d_in[4];
    const float* ln_g   = (const float*)d_in[5];
    const float* ln_b   = (const float*)d_in[6];
    const float* W_u    = (const float*)d_in[7];
    const float* b_u    = (const float*)d_in[8];
    const float* W_v    = (const float*)d_in[9];
    const float* b_v    = (const float*)d_in[10];
    const float* W_z    = (const float*)d_in[11];
    const float* b_z    = (const float*)d_in[12];
    const float* gamma  = (const float*)d_in[13];
    const float* beta   = (const float*)d_in[14];
    const float* embed  = (const float*)d_in[15];
    const float* W_out  = (const float*)d_in[16];
    const float* b_out  = (const float*)d_in[17];
    const float* W_gate = (const float*)d_in[18];
    const float* b_gate = (const float*)d_in[19];
    float* out = (float*)d_out;

    // workspace (~299 MiB)
    char* ws = (char*)d_ws;
    float* Z    = (float*)ws;                     ws += (size_t)16384 * 128 * 4;
    float* qpos = (float*)ws;                     ws += (size_t)16384 * 11 * 4;
    float* part = (float*)ws;                     ws += (size_t)16384 * 32 * 4;
    float* inv  = (float*)ws;                     ws += (size_t)16384 * 4;
    unsigned short* seq_bf = (unsigned short*)ws; ws += (size_t)16384 * 768 * 2;
    unsigned short* G_bf   = (unsigned short*)ws; ws += (size_t)16384 * 768 * 2;
    unsigned short* x_bf   = (unsigned short*)ws; ws += (size_t)16384 * 768 * 2;
    unsigned short* U_bf   = (unsigned short*)ws; ws += (size_t)16384 * 1536 * 2;
    unsigned short* Vt     = (unsigned short*)ws; ws += (size_t)16384 * 1536 * 2;
    unsigned short* out_bf = (unsigned short*)ws; ws += (size_t)16384 * 768 * 2;
    unsigned short* Qb     = (unsigned short*)ws; ws += (size_t)16384 * 128 * 2;
    unsigned short* Kb     = (unsigned short*)ws; ws += (size_t)16384 * 128 * 2;
    unsigned short* E      = (unsigned short*)ws; ws += (size_t)8 * 2048 * 2048 * 2;
    unsigned short* Wit    = (unsigned short*)ws; ws += (size_t)768 * 768 * 2;
    unsigned short* Wuvzt  = (unsigned short*)ws; ws += (size_t)3200 * 768 * 2;
    unsigned short* Wot    = (unsigned short*)ws; ws += (size_t)768 * 1536 * 2;
    unsigned short* Wgt    = (unsigned short*)ws; ws += (size_t)768 * 1536 * 2;

    const dim3 b256(256);

    // 0. conversions (2 launches)
    f32_to_bf16<<<12288, b256, 0, stream>>>(seq, seq_bf);
    prep_w<<<5280, b256, 0, stream>>>(W_init, W_u, W_v, W_z, W_out, W_gate,
                                      Wit, Wuvzt, Wot, Wgt);

    // 1. G_bf = bf16(seq @ W_init + b_init)
    mfma_gemm<2, false><<<dim3(6, 128), b256, 0, stream>>>(
        seq_bf, 768, 0, Wit, 768, 0, nullptr, nullptr,
        b_init, nullptr, nullptr, 0, nullptr, G_bf, 0, nullptr, 768, 768);
    // 2. x_bf = LN(G_bf)
    ln_bf16<<<16384, b256, 0, stream>>>(G_bf, ln_g, ln_b, x_bf);
    // 3. merged U | Vt | Z = silu(x @ [W_u|W_v|W_z] + [b_u|b_v|b_z])
    mfma_gemm<8, false><<<dim3(25, 128), b256, 0, stream>>>(
        x_bf, 768, 0, Wuvzt, 768, 0, nullptr, nullptr,
        b_u, b_v, b_z, 0, Z, U_bf, 0, Vt, 3200, 768);
    // 4. q_pos + Qb/Kb (one launch, one Z read)
    qk_prep<<<4096, b256, 0, stream>>>(Z, gamma, beta, embed, qpos, Qb, Kb);

    // 5. attention; softmax fused (exp + rowsum inv)
    mfma_gemm<1, false><<<dim3(16, 16, 8), b256, 0, stream>>>(
        Qb, 128, 2048L * 128, Kb, 128, 2048L * 128,
        nullptr, nullptr, nullptr, nullptr,
        qpos, 2048L * 11, part,
        E, 2048L * 2048, nullptr, 2048, 128);
    reduce_inv<<<64, b256, 0, stream>>>(part, inv);
    mfma_gemm<0, false><<<dim3(12, 16, 8), b256, 0, stream>>>(
        E, 2048, 2048L * 2048, Vt, 2048, 1536L * 2048,
        nullptr, nullptr, nullptr, nullptr, nullptr, 0, inv,
        U_bf, 2048L * 1536, nullptr, 1536, 2048);

    // 6. out = UV @ W_out + b_out (fp32 -> d_out, bf16 -> out_bf)
    mfma_gemm<6, false><<<dim3(6, 128), b256, 0, stream>>>(
        U_bf, 1536, 0, Wot, 1536, 0, nullptr, nullptr,
        b_out, nullptr, nullptr, 0, nullptr, out, 0, out_bf, 768, 1536);
    // 7. fused gate: g = sig(out_pre@Wg1 + seq@Wg2 + b); out = g*out + (1-g)*seq
    mfma_gemm<7, true><<<dim3(6, 128), b256, 0, stream>>>(
        out_bf, 768, 0, Wgt, 1536, 0, seq_bf, Wgt + 768,
        b_gate, nullptr, seq, 0, nullptr, out, 0, nullptr, 768, 768);
}

// Round 6
// 718.875 us; speedup vs baseline: 1.3787x; 1.1538x over previous
//
#include <hip/hip_runtime.h>
#include <math.h>

// GAU block. N=8, S=2048, D=768, DK=128, 2D=1536. NS=16384 rows.
// Round 12: fix the round-11 UVZ occupancy regression. Evidence: merged UVZ
// GEMM ran 164us @ VGPR 96 / Occupancy 20.4% vs round-3 UV 115us @ VGPR 80 /
// 29.6% -- the 3-path epilogue raised register pressure and cost a block/CU.
// Fix: (a) per-instantiation __launch_bounds__(256, MW) with MW=6 for the
// UVZ kernel (VGPR cap ~85; spills, if any, land in the once-run epilogue);
// (b) EPI-8 epilogue restructured as a block-uniform branch on bx (each
// block is single-case by construction: bx<12 U, bx<24 Vt, bx==24 Z).
// Also: f32_to_bf16 folded into prep_w (one fewer launch).
// All GEMM arithmetic is op-for-op identical to the 825us round-9 run.

typedef __bf16 bf16x8 __attribute__((ext_vector_type(8)));
typedef float  f32x4  __attribute__((ext_vector_type(4)));

__device__ __forceinline__ float silu_f(float v) { return v / (1.0f + __expf(-v)); }
__device__ __forceinline__ float sigmoid_f(float v) { return 1.0f / (1.0f + __expf(-v)); }

__device__ __forceinline__ unsigned short f2bf(float f) {
    union { float f; unsigned u; } v; v.f = f;
    unsigned r = v.u + 0x7fff + ((v.u >> 16) & 1);
    return (unsigned short)(r >> 16);
}
__device__ __forceinline__ float bf2f(unsigned short h) {
    union { unsigned u; float f; } v; v.u = ((unsigned)h) << 16; return v.f;
}

__device__ __forceinline__ void gload_lds16(const void* g, void* l) {
    __builtin_amdgcn_global_load_lds((const __attribute__((address_space(1))) char*)g,
                                     (__attribute__((address_space(3))) char*)l, 16, 0, 0);
}

// XCD-aware bijective block swizzle. Every per-z grid in this file has
// gx*gy % 8 == 0. Confirmed twice: -21..27% FETCH_SIZE on the PV GEMM.
__device__ __forceinline__ void xcd_swizzle(int& bx, int& by) {
    const int nbx = gridDim.x;
    int flat = by * nbx + bx;
    const int per = (nbx * gridDim.y) >> 3;
    flat = (flat & 7) * per + (flat >> 3);
    bx = flat % nbx;
    by = flat / nbx;
}

// ---------------------------------------------------------------------------
// bf16 MFMA GEMM: acc[M,N] = A[M,K] @ Bt[N,K]^T (+2nd pass if DUAL).
// 128x128 tile, BK=64, 256 thr / 4 waves 2x2, each wave 4x4 of 16x16x32.
// LDS rows hold 8 16B slots, stored at slot p = s ^ (r&7) -> 2-way reads.
// MW = min waves per EU (2nd __launch_bounds__ arg); 6 caps VGPR ~85.
// Epilogues:
//  0 PV   : Ub[m,n] = bf16(acc * inv[z*2048+m] * bf2f(Ub[m,n]))  (aux2=inv)
//  1 QK   : E[m,n] = bf16(exp((acc+qpos[m,clip(n-m)+5])/16)); 16-lane partial
//           row sums -> aux2[(z*2048+m)*32 + bx*2 + (wave&1)]     (aux=qpos)
//  2 BIAS : Cbf[m,n] = bf16(acc + bias[n])
//  6 OUT  : Of[m,n] = acc + bias[n]  AND  Obf[m,n] = bf16(same)
//  7 GATE : g = sig(acc + bias[n]); Of[m,n] = g*Of + (1-g)*res    (aux=res)
//  8 UVZ  : bx<12: Ub = bf16(silu(acc+bias[n])); bx<24:
//           Vt[bat][(n-1536)*2048+(m&2047)] = bf16(silu(acc+bias2[n-1536]));
//           bx==24: Zf[m*128+(n-3072)] = silu(acc+aux[n-3072]) fp32 (aux2=Zf)
// ---------------------------------------------------------------------------
template <int EPI, bool DUAL, int MW>
__global__ __launch_bounds__(256, MW) void mfma_gemm(
    const unsigned short* __restrict__ A,  int lda, long sA,
    const unsigned short* __restrict__ Bt, int ldb, long sB,
    const unsigned short* __restrict__ A2,
    const unsigned short* __restrict__ Bt2,
    const float* __restrict__ bias,
    const float* __restrict__ bias2,
    const float* __restrict__ aux, long sAux,
    float* __restrict__ aux2,
    void* __restrict__ P0, long sP0,
    void* __restrict__ P1,
    int N, int K)
{
    __shared__ unsigned short As[128 * 64];
    __shared__ unsigned short Bs[128 * 64];
    const int tid  = threadIdx.x;
    const int lane = tid & 63;
    const int wave = tid >> 6;
    const int z    = blockIdx.z;
    int bx = blockIdx.x, by = blockIdx.y;
    xcd_swizzle(bx, by);
    const int row0 = by * 128;
    const int col0 = bx * 128;

    int c_r[4], c_g[4];
    unsigned short* alp[4];
    unsigned short* blp[4];
#pragma unroll
    for (int ci = 0; ci < 4; ++ci) {
        const int c = ci * 256 + tid;
        const int r = c >> 3;
        c_r[ci] = r;
        c_g[ci] = (c & 7) ^ (r & 7);   // global slot fetched into LDS pos c
        alp[ci] = &As[c * 8];
        blp[ci] = &Bs[c * 8];
    }

    const int wr = (wave >> 1) * 64;
    const int wc = (wave & 1) * 64;
    const int fm  = lane & 15;
    const int kbi = lane >> 4;
    const int er  = kbi * 4;

    int aoff[2][4], boff[2][4];
#pragma unroll
    for (int b = 0; b < 2; ++b)
#pragma unroll
        for (int i = 0; i < 4; ++i) {
            const int r = wr + i * 16 + fm;
            aoff[b][i] = r * 64 + (((b * 4 + kbi) ^ (r & 7)) * 8);
            const int n = wc + i * 16 + fm;
            boff[b][i] = n * 64 + (((b * 4 + kbi) ^ (n & 7)) * 8);
        }

    f32x4 acc[4][4];
#pragma unroll
    for (int i = 0; i < 4; ++i)
#pragma unroll
        for (int j = 0; j < 4; ++j) acc[i][j] = (f32x4){0.f, 0.f, 0.f, 0.f};

    const int npass = DUAL ? 2 : 1;
    for (int pass = 0; pass < npass; ++pass) {
        const unsigned short* Ab = (pass ? A2  : A)  + (size_t)z * sA;
        const unsigned short* Bb = (pass ? Bt2 : Bt) + (size_t)z * sB;
        const unsigned short* ag[4];
        const unsigned short* bg[4];
#pragma unroll
        for (int ci = 0; ci < 4; ++ci) {
            ag[ci] = Ab + (size_t)(row0 + c_r[ci]) * lda + c_g[ci] * 8;
            bg[ci] = Bb + (size_t)(col0 + c_r[ci]) * ldb + c_g[ci] * 8;
        }
        for (int k0 = 0; k0 < K; k0 += 64) {
#pragma unroll
            for (int ci = 0; ci < 4; ++ci) { gload_lds16(ag[ci], alp[ci]); ag[ci] += 64; }
#pragma unroll
            for (int ci = 0; ci < 4; ++ci) { gload_lds16(bg[ci], blp[ci]); bg[ci] += 64; }
            __syncthreads();
#pragma unroll
            for (int b = 0; b < 2; ++b) {
                bf16x8 a[4], bb[4];
#pragma unroll
                for (int i = 0; i < 4; ++i) a[i]  = *(const bf16x8*)&As[aoff[b][i]];
#pragma unroll
                for (int j = 0; j < 4; ++j) bb[j] = *(const bf16x8*)&Bs[boff[b][j]];
#pragma unroll
                for (int i = 0; i < 4; ++i)
#pragma unroll
                    for (int j = 0; j < 4; ++j)
                        acc[i][j] = __builtin_amdgcn_mfma_f32_16x16x32_bf16(
                            a[i], bb[j], acc[i][j], 0, 0, 0);
            }
            __syncthreads();
        }
    }

    if (EPI == 0) {
        unsigned short* Ub = (unsigned short*)P0 + (size_t)z * sP0;
        const float* inv = aux2 + (z << 11);
#pragma unroll
        for (int i = 0; i < 4; ++i)
#pragma unroll
            for (int j = 0; j < 4; ++j) {
                const int m0 = row0 + wr + i * 16 + er;
                const int n  = col0 + wc + j * 16 + fm;
#pragma unroll
                for (int reg = 0; reg < 4; ++reg) {
                    const size_t idx = (size_t)(m0 + reg) * N + n;
                    Ub[idx] = f2bf(acc[i][j][reg] * inv[m0 + reg] * bf2f(Ub[idx]));
                }
            }
    } else if (EPI == 1) {
        const float* qb = aux + (size_t)z * sAux;
        unsigned short* Eb = (unsigned short*)P0 + (size_t)z * sP0;
#pragma unroll
        for (int i = 0; i < 4; ++i) {
            float rs[4] = {0.f, 0.f, 0.f, 0.f};
#pragma unroll
            for (int j = 0; j < 4; ++j) {
                const int n = col0 + wc + j * 16 + fm;
#pragma unroll
                for (int reg = 0; reg < 4; ++reg) {
                    const int m = row0 + wr + i * 16 + er + reg;
                    int d = n - m;
                    d = d < -5 ? -5 : (d > 5 ? 5 : d);
                    const float v =
                        __expf((acc[i][j][reg] + qb[m * 11 + d + 5]) * 0.0625f);
                    const unsigned short h = f2bf(v);
                    Eb[(size_t)m * N + n] = h;
                    rs[reg] += bf2f(h);
                }
            }
#pragma unroll
            for (int reg = 0; reg < 4; ++reg) {
                float s = rs[reg];
                s += __shfl_xor(s, 1); s += __shfl_xor(s, 2);
                s += __shfl_xor(s, 4); s += __shfl_xor(s, 8);
                if (fm == 0) {
                    const int m = row0 + wr + i * 16 + er + reg;
                    aux2[((size_t)(z * 2048 + m)) * 32 + bx * 2 + (wave & 1)] = s;
                }
            }
        }
    } else if (EPI == 2) {
        unsigned short* Cb = (unsigned short*)P0;
#pragma unroll
        for (int j = 0; j < 4; ++j) {
            const int n = col0 + wc + j * 16 + fm;
            const float bb = bias[n];
#pragma unroll
            for (int i = 0; i < 4; ++i) {
                const int m0 = row0 + wr + i * 16 + er;
#pragma unroll
                for (int reg = 0; reg < 4; ++reg)
                    Cb[(size_t)(m0 + reg) * N + n] = f2bf(acc[i][j][reg] + bb);
            }
        }
    } else if (EPI == 6) {
        float* Of = (float*)P0;
        unsigned short* Ob = (unsigned short*)P1;
#pragma unroll
        for (int j = 0; j < 4; ++j) {
            const int n = col0 + wc + j * 16 + fm;
            const float bb = bias[n];
#pragma unroll
            for (int i = 0; i < 4; ++i) {
                const int m0 = row0 + wr + i * 16 + er;
#pragma unroll
                for (int reg = 0; reg < 4; ++reg) {
                    const float v = acc[i][j][reg] + bb;
                    const size_t idx = (size_t)(m0 + reg) * N + n;
                    Of[idx] = v;
                    Ob[idx] = f2bf(v);
                }
            }
        }
    } else if (EPI == 7) {
        float* Of = (float*)P0;
        const float* res = aux;
#pragma unroll
        for (int j = 0; j < 4; ++j) {
            const int n = col0 + wc + j * 16 + fm;
            const float bb = bias[n];
#pragma unroll
            for (int i = 0; i < 4; ++i) {
                const int m0 = row0 + wr + i * 16 + er;
#pragma unroll
                for (int reg = 0; reg < 4; ++reg) {
                    const float g = sigmoid_f(acc[i][j][reg] + bb);
                    const size_t idx = (size_t)(m0 + reg) * N + n;
                    Of[idx] = g * Of[idx] + (1.0f - g) * res[idx];
                }
            }
        }
    } else {  // EPI 8: merged U | Vt | Z — block-uniform on bx
        if (bx < 12) {
            unsigned short* Ub = (unsigned short*)P0;
#pragma unroll
            for (int j = 0; j < 4; ++j) {
                const int n = col0 + wc + j * 16 + fm;
                const float bb = bias[n];
#pragma unroll
                for (int i = 0; i < 4; ++i) {
                    const int m0 = row0 + wr + i * 16 + er;
#pragma unroll
                    for (int reg = 0; reg < 4; ++reg)
                        Ub[(size_t)(m0 + reg) * 1536 + n] =
                            f2bf(silu_f(acc[i][j][reg] + bb));
                }
            }
        } else if (bx < 24) {
            unsigned short* Vt = (unsigned short*)P1;
#pragma unroll
            for (int j = 0; j < 4; ++j) {
                const int n = col0 + wc + j * 16 + fm;
                const float bb = bias2[n - 1536];
#pragma unroll
                for (int i = 0; i < 4; ++i) {
                    const int m0 = row0 + wr + i * 16 + er;
                    const int bat = m0 >> 11;
                    const int sl  = m0 & 2047;
                    unsigned short t[4];
#pragma unroll
                    for (int reg = 0; reg < 4; ++reg)
                        t[reg] = f2bf(silu_f(acc[i][j][reg] + bb));
                    *(ushort4*)(Vt + (size_t)bat * 1536 * 2048
                                + (size_t)(n - 1536) * 2048 + sl) = *(const ushort4*)t;
                }
            }
        } else {
            float* Zf = aux2;
#pragma unroll
            for (int j = 0; j < 4; ++j) {
                const int n = col0 + wc + j * 16 + fm;
                const float bb = aux[n - 3072];
#pragma unroll
                for (int i = 0; i < 4; ++i) {
                    const int m0 = row0 + wr + i * 16 + er;
#pragma unroll
                    for (int reg = 0; reg < 4; ++reg)
                        Zf[(size_t)(m0 + reg) * 128 + (n - 3072)] =
                            silu_f(acc[i][j][reg] + bb);
                }
            }
        }
    }
}

// rowsum inverse: inv[r] = 1 / sum_k part[r][k], r in [0,16384)
__global__ __launch_bounds__(256) void reduce_inv(
    const float* __restrict__ part, float* __restrict__ inv)
{
    const int r = blockIdx.x * 256 + threadIdx.x;
    const float4* p = (const float4*)(part + (size_t)r * 32);
    float s = 0.f;
#pragma unroll
    for (int k = 0; k < 8; ++k) {
        float4 v = p[k];
        s += v.x + v.y + v.z + v.w;
    }
    inv[r] = 1.0f / s;
}

// All input prep in one launch. Flat grid:
// [0,12288)      : seq fp32 -> bf16 (4 elems/thread)
// [12288,12864)  : W_init -> Wit        (768x768)
// [12864,14016)  : W_u    -> Wuvzt      (768x1536)
// [14016,15168)  : W_v    -> Wuvzt+1536*768
// [15168,15264)  : W_z    -> Wuvzt+3072*768 (768x128)
// [15264,16416)  : W_out  -> Wot        (1536x768)
// [16416,17568)  : W_gate -> Wgt        (1536x768)
__global__ __launch_bounds__(256) void prep_all(
    const float* __restrict__ seq, unsigned short* __restrict__ seq_bf,
    const float* __restrict__ Wi, const float* __restrict__ Wu,
    const float* __restrict__ Wv, const float* __restrict__ Wz,
    const float* __restrict__ Wo, const float* __restrict__ Wg,
    unsigned short* __restrict__ Wit, unsigned short* __restrict__ Wuvzt,
    unsigned short* __restrict__ Wot, unsigned short* __restrict__ Wgt)
{
    const int b = blockIdx.x;
    if (b < 12288) {
        const size_t i = ((size_t)b * 256 + threadIdx.x) * 4;
        float4 v = *(const float4*)(seq + i);
        ushort4 o;
        o.x = f2bf(v.x); o.y = f2bf(v.y); o.z = f2bf(v.z); o.w = f2bf(v.w);
        *(ushort4*)(seq_bf + i) = o;
        return;
    }
    const int bb = b - 12288;
    const float* W;
    unsigned short* Wt;
    int K, N, t;
    if (bb < 576)       { W = Wi; Wt = Wit;  K = 768;  N = 768;  t = bb; }
    else if (bb < 1728) { W = Wu; Wt = Wuvzt;                        K = 768; N = 1536; t = bb - 576; }
    else if (bb < 2880) { W = Wv; Wt = Wuvzt + (size_t)1536 * 768;   K = 768; N = 1536; t = bb - 1728; }
    else if (bb < 2976) { W = Wz; Wt = Wuvzt + (size_t)3072 * 768;   K = 768; N = 128;  t = bb - 2880; }
    else if (bb < 4128) { W = Wo; Wt = Wot;  K = 1536; N = 768;  t = bb - 2976; }
    else                { W = Wg; Wt = Wgt;  K = 1536; N = 768;  t = bb - 4128; }
    const int nbx = N >> 5;
    const int kb = (t / nbx) * 32, nb = (t % nbx) * 32;

    __shared__ float tile[32][33];
    const int tx = threadIdx.x & 31, ty = threadIdx.x >> 5;
#pragma unroll
    for (int r = 0; r < 4; ++r)
        tile[ty + 8 * r][tx] = W[(size_t)(kb + ty + 8 * r) * N + nb + tx];
    __syncthreads();
#pragma unroll
    for (int r = 0; r < 4; ++r)
        Wt[(size_t)(nb + ty + 8 * r) * K + kb + tx] = f2bf(tile[tx][ty + 8 * r]);
}

// LayerNorm over 768, bf16 in/out, fp32 stats. grid = 16384 rows.
__global__ __launch_bounds__(256) void ln_bf16(
    const unsigned short* __restrict__ in, const float* __restrict__ g,
    const float* __restrict__ b, unsigned short* __restrict__ out)
{
    const int row = blockIdx.x;
    const unsigned short* p = in + (size_t)row * 768;
    const int tid = threadIdx.x;
    float v0 = bf2f(p[tid]), v1 = bf2f(p[tid + 256]), v2 = bf2f(p[tid + 512]);
    float s = v0 + v1 + v2;
    float q = v0 * v0 + v1 * v1 + v2 * v2;
#pragma unroll
    for (int off = 32; off; off >>= 1) {
        s += __shfl_xor(s, off);
        q += __shfl_xor(q, off);
    }
    __shared__ float ss[4], qq[4];
    const int wid = tid >> 6, lane = tid & 63;
    if (lane == 0) { ss[wid] = s; qq[wid] = q; }
    __syncthreads();
    s = ss[0] + ss[1] + ss[2] + ss[3];
    q = qq[0] + qq[1] + qq[2] + qq[3];
    const float mu  = s * (1.0f / 768.0f);
    const float var = q * (1.0f / 768.0f) - mu * mu;
    const float inv = rsqrtf(var + 1e-5f);
    unsigned short* o = out + (size_t)row * 768;
    o[tid]       = f2bf((v0 - mu) * inv * g[tid]       + b[tid]);
    o[tid + 256] = f2bf((v1 - mu) * inv * g[tid + 256] + b[tid + 256]);
    o[tid + 512] = f2bf((v2 - mu) * inv * g[tid + 512] + b[tid + 512]);
}

// Merged Q/K affine + q_pos. One wave per row (4 rows/block, grid 4096).
__global__ __launch_bounds__(256) void qk_prep(
    const float* __restrict__ Z, const float* __restrict__ gamma,
    const float* __restrict__ beta, const float* __restrict__ ep,
    float* __restrict__ qpos,
    unsigned short* __restrict__ Qb, unsigned short* __restrict__ Kb)
{
    const int tid = threadIdx.x;
    const int lane = tid & 63;
    const int wid = tid >> 6;
    const int row = blockIdx.x * 4 + wid;
    const float z0 = Z[(size_t)row * 128 + lane];
    const float z1 = Z[(size_t)row * 128 + 64 + lane];
    Qb[(size_t)row * 128 + lane]      = f2bf(z0 * gamma[lane]       + beta[lane]);
    Qb[(size_t)row * 128 + 64 + lane] = f2bf(z1 * gamma[64 + lane]  + beta[64 + lane]);
    Kb[(size_t)row * 128 + lane]      = f2bf(z0 * gamma[256 + lane]      + beta[256 + lane]);
    Kb[(size_t)row * 128 + 64 + lane] = f2bf(z1 * gamma[256 + 64 + lane] + beta[256 + 64 + lane]);
    const float q0 = z0 * gamma[128 + lane] + beta[128 + lane];
    const float q1 = z1 * gamma[192 + lane] + beta[192 + lane];
#pragma unroll
    for (int p = 0; p < 11; ++p) {
        float s = q0 * ep[p * 128 + lane] + q1 * ep[p * 128 + 64 + lane];
#pragma unroll
        for (int off = 32; off; off >>= 1) s += __shfl_xor(s, off);
        if (lane == 0) qpos[(size_t)row * 11 + p] = s;
    }
}

// ---------------------------------------------------------------------------
extern "C" void kernel_launch(void* const* d_in, const int* in_sizes, int n_in,
                              void* d_out, int out_size, void* d_ws, size_t ws_size,
                              hipStream_t stream)
{
    const float* seq    = (const float*)d_in[0];
    const float* W_init = (const float*)d_in[3];
    const float* b_init = (const float*)d_in[4];
    const float* ln_g   = (const float*)d_in[5];
    const float* ln_b   = (const float*)d_in[6];
    const float* W_u    = (const float*)d_in[7];
    const float* b_u    = (const float*)d_in[8];
    const float* W_v    = (const float*)d_in[9];
    const float* b_v    = (const float*)d_in[10];
    const float* W_z    = (const float*)d_in[11];
    const float* b_z    = (const float*)d_in[12];
    const float* gamma  = (const float*)d_in[13];
    const float* beta   = (const float*)d_in[14];
    const float* embed  = (const float*)d_in[15];
    const float* W_out  = (const float*)d_in[16];
    const float* b_out  = (const float*)d_in[17];
    const float* W_gate = (const float*)d_in[18];
    const float* b_gate = (const float*)d_in[19];
    float* out = (float*)d_out;

    // workspace (~299 MiB)
    char* ws = (char*)d_ws;
    float* Z    = (float*)ws;                     ws += (size_t)16384 * 128 * 4;
    float* qpos = (float*)ws;                     ws += (size_t)16384 * 11 * 4;
    float* part = (float*)ws;                     ws += (size_t)16384 * 32 * 4;
    float* inv  = (float*)ws;                     ws += (size_t)16384 * 4;
    unsigned short* seq_bf = (unsigned short*)ws; ws += (size_t)16384 * 768 * 2;
    unsigned short* G_bf   = (unsigned short*)ws; ws += (size_t)16384 * 768 * 2;
    unsigned short* x_bf   = (unsigned short*)ws; ws += (size_t)16384 * 768 * 2;
    unsigned short* U_bf   = (unsigned short*)ws; ws += (size_t)16384 * 1536 * 2;
    unsigned short* Vt     = (unsigned short*)ws; ws += (size_t)16384 * 1536 * 2;
    unsigned short* out_bf = (unsigned short*)ws; ws += (size_t)16384 * 768 * 2;
    unsigned short* Qb     = (unsigned short*)ws; ws += (size_t)16384 * 128 * 2;
    unsigned short* Kb     = (unsigned short*)ws; ws += (size_t)16384 * 128 * 2;
    unsigned short* E      = (unsigned short*)ws; ws += (size_t)8 * 2048 * 2048 * 2;
    unsigned short* Wit    = (unsigned short*)ws; ws += (size_t)768 * 768 * 2;
    unsigned short* Wuvzt  = (unsigned short*)ws; ws += (size_t)3200 * 768 * 2;
    unsigned short* Wot    = (unsigned short*)ws; ws += (size_t)768 * 1536 * 2;
    unsigned short* Wgt    = (unsigned short*)ws; ws += (size_t)768 * 1536 * 2;

    const dim3 b256(256);

    // 0. all input prep (seq conversion + 6 weight transposes), one launch
    prep_all<<<17568, b256, 0, stream>>>(seq, seq_bf,
                                         W_init, W_u, W_v, W_z, W_out, W_gate,
                                         Wit, Wuvzt, Wot, Wgt);

    // 1. G_bf = bf16(seq @ W_init + b_init)
    mfma_gemm<2, false, 4><<<dim3(6, 128), b256, 0, stream>>>(
        seq_bf, 768, 0, Wit, 768, 0, nullptr, nullptr,
        b_init, nullptr, nullptr, 0, nullptr, G_bf, 0, nullptr, 768, 768);
    // 2. x_bf = LN(G_bf)
    ln_bf16<<<16384, b256, 0, stream>>>(G_bf, ln_g, ln_b, x_bf);
    // 3. merged U | Vt | Z = silu(x @ [W_u|W_v|W_z] + [b_u|b_v|b_z])  [MW=6]
    mfma_gemm<8, false, 6><<<dim3(25, 128), b256, 0, stream>>>(
        x_bf, 768, 0, Wuvzt, 768, 0, nullptr, nullptr,
        b_u, b_v, b_z, 0, Z, U_bf, 0, Vt, 3200, 768);
    // 4. q_pos + Qb/Kb (one launch, one Z read)
    qk_prep<<<4096, b256, 0, stream>>>(Z, gamma, beta, embed, qpos, Qb, Kb);

    // 5. attention; softmax fused (exp + rowsum inv)
    mfma_gemm<1, false, 4><<<dim3(16, 16, 8), b256, 0, stream>>>(
        Qb, 128, 2048L * 128, Kb, 128, 2048L * 128,
        nullptr, nullptr, nullptr, nullptr,
        qpos, 2048L * 11, part,
        E, 2048L * 2048, nullptr, 2048, 128);
    reduce_inv<<<64, b256, 0, stream>>>(part, inv);
    mfma_gemm<0, false, 4><<<dim3(12, 16, 8), b256, 0, stream>>>(
        E, 2048, 2048L * 2048, Vt, 2048, 1536L * 2048,
        nullptr, nullptr, nullptr, nullptr, nullptr, 0, inv,
        U_bf, 2048L * 1536, nullptr, 1536, 2048);

    // 6. out = UV @ W_out + b_out (fp32 -> d_out, bf16 -> out_bf)
    mfma_gemm<6, false, 4><<<dim3(6, 128), b256, 0, stream>>>(
        U_bf, 1536, 0, Wot, 1536, 0, nullptr, nullptr,
        b_out, nullptr, nullptr, 0, nullptr, out, 0, out_bf, 768, 1536);
    // 7. fused gate: g = sig(out_pre@Wg1 + seq@Wg2 + b); out = g*out + (1-g)*seq
    mfma_gemm<7, true, 4><<<dim3(6, 128), b256, 0, stream>>>(
        out_bf, 768, 0, Wgt, 1536, 0, seq_bf, Wgt + 768,
        b_gate, nullptr, seq, 0, nullptr, out, 0, nullptr, 768, 768);
}